// Round 3
// baseline (85.035 us; speedup 1.0000x reference)
//
#include <hip/hip_runtime.h>
#include <math.h>

// DRMM fused pipeline for MI355X (gfx950) — round 3: concurrency-focused.
// Phase 1: gather + cosine-sim + histogram. 2048 blocks x 256 thr.
//   block = (bd, qhalf, tokhalf): 4 query terms, 256 tokens.
//   qs[4][8] = 32 VGPR -> <=64 VGPR total -> 8 waves/SIMD (32 waves/CU).
//   Hist accumulated into d_ws (fp32 global atomics, exact integer counts).
// Phase 2: MLP 30->128->64->32->1 + gate softmax + output. 512 blocks x 512 thr.
// B=32, D=16, L=512, Q=8, E=128, NB=30

#define BN_INV 0.99950037468777346f  // np.float32(1/sqrt(1+1e-3))

__device__ __forceinline__ float shflx(float v, int m) {
    return __shfl_xor(v, m, 64);
}

__device__ __forceinline__ float sel4(const float* v, int i) {
    float a = (i & 1) ? v[1] : v[0];
    float b = (i & 1) ? v[3] : v[2];
    return (i & 2) ? b : a;
}

// ---------------- Phase 1: gather + histogram ----------------
__global__ __launch_bounds__(256, 8)
void drmm_hist(const int* __restrict__ doc,
               const int* __restrict__ query,
               const float* __restrict__ emb,
               float* __restrict__ hist_g)   // [512][8][30] fp32, pre-zeroed
{
    __shared__ float histw[4][4][33];  // [wave][q_local][bin(+pad)]
    __shared__ float qn_s[4];

    const int tid = threadIdx.x;
    const int bid = blockIdx.x;
    const int bd  = bid >> 2;          // 0..511
    const int qh  = (bid >> 1) & 1;    // query half
    const int th  = bid & 1;           // token half
    const int b   = bd >> 4;
    const int g   = tid >> 4;          // 16-lane group 0..15
    const int t16 = tid & 15;
    const int wid = tid >> 6;          // wave 0..3

    for (int i = tid; i < 4 * 4 * 33; i += 256) ((float*)histw)[i] = 0.0f;

    // 4 query vectors for this block; lane holds its 8-float e-slice (32 VGPR).
    float qs[4][8];
#pragma unroll
    for (int q = 0; q < 4; ++q) {
        int qi = query[b * 8 + qh * 4 + q];
        const float4* qr = (const float4*)((const char*)emb +
                            (unsigned)qi * 512u + (unsigned)(t16 * 32));
        float4 x0 = qr[0], x1 = qr[1];
        qs[q][0] = x0.x; qs[q][1] = x0.y; qs[q][2] = x0.z; qs[q][3] = x0.w;
        qs[q][4] = x1.x; qs[q][5] = x1.y; qs[q][6] = x1.z; qs[q][7] = x1.w;
    }

    // Query norms: groups 0..3 reduce q = g (same op order as prior rounds).
    if (g < 4) {
        float p[4];
#pragma unroll
        for (int q = 0; q < 4; ++q) {
            float s = 0.f;
#pragma unroll
            for (int j = 0; j < 8; ++j) s += qs[q][j] * qs[q][j];
            p[q] = s;
        }
        float s = sel4(p, g);
        s += shflx(s, 1); s += shflx(s, 2); s += shflx(s, 4); s += shflx(s, 8);
        if (t16 == 0) qn_s[g] = sqrtf(s);
    }
    __syncthreads();

    const float qn_r = (t16 < 4) ? qn_s[t16] : 0.f;
    const int* docrow = doc + (size_t)bd * 512 + th * 256;

    // 256 tokens / 16 groups = 16 iterations.
#pragma unroll 2
    for (int it = 0; it < 16; ++it) {
        int idx = docrow[it * 16 + g];
        const float4* r = (const float4*)((const char*)emb +
                            (unsigned)idx * 512u + (unsigned)(t16 * 32));
        float4 x0 = r[0], x1 = r[1];
        float v[8] = {x0.x, x0.y, x0.z, x0.w, x1.x, x1.y, x1.z, x1.w};

        float dd = 0.f;
#pragma unroll
        for (int j = 0; j < 8; ++j) dd += v[j] * v[j];
        float dq[4];
#pragma unroll
        for (int q = 0; q < 4; ++q) {
            float s = 0.f;
#pragma unroll
            for (int j = 0; j < 8; ++j) s += v[j] * qs[q][j];
            dq[q] = s;
        }
        // butterfly over the 16-lane group — same order as rounds 1-2
#pragma unroll
        for (int off = 8; off >= 1; off >>= 1) {
            dd += shflx(dd, off);
#pragma unroll
            for (int q = 0; q < 4; ++q) dq[q] += shflx(dq[q], off);
        }
        if (t16 < 4) {
            float dqq = sel4(dq, t16);
            float sim = dqq / (sqrtf(dd) * qn_r + 1e-8f);
            float u = (sim - 0.001f) / 0.999f * 30.0f;   // ref op order
            int bin = (int)floorf(u);
            bin = bin < 0 ? 0 : (bin > 29 ? 29 : bin);
            atomicAdd(&histw[wid][t16][bin], 1.0f);
        }
    }
    __syncthreads();

    // flush: sum 4 wave-private hists, one global atomic per (q,bin).
    if (tid < 120) {
        int q4 = tid / 30, k = tid - q4 * 30;
        float s = histw[0][q4][k] + histw[1][q4][k]
                + histw[2][q4][k] + histw[3][q4][k];
        atomicAdd(&hist_g[bd * 240 + (qh * 4 + q4) * 30 + k], s);
    }
}

// ---------------- Phase 2: gate softmax + MLP + output ----------------
__global__ __launch_bounds__(512, 4)
void drmm_mlp(const float* __restrict__ hist_g,
              const int* __restrict__ query,
              const float* __restrict__ idf,
              const float* __restrict__ w_gate,
              const float* __restrict__ g_in, const float* __restrict__ b_in,
              const float* __restrict__ W0, const float* __restrict__ b0,
              const float* __restrict__ g0, const float* __restrict__ be0,
              const float* __restrict__ W1, const float* __restrict__ b1,
              const float* __restrict__ g1, const float* __restrict__ be1,
              const float* __restrict__ W2, const float* __restrict__ b2,
              const float* __restrict__ g2, const float* __restrict__ be2,
              const float* __restrict__ W3, const float* __restrict__ b3,
              const float* __restrict__ g3, const float* __restrict__ be3,
              float* __restrict__ out)
{
    __shared__ float xrow[8][30];
    __shared__ float h1s[8][128];
    __shared__ float h2s[8][64];
    __shared__ float h3s[8][32];
    __shared__ float gate_s[8];
    __shared__ float part[8];

    const int tid  = threadIdx.x;
    const int bd   = blockIdx.x;
    const int b    = bd >> 4;
    const int wid  = tid >> 6;
    const int lane = tid & 63;

    // Gate softmax: 8 parallel lanes (same op order as round 2).
    if (tid >= 504) {
        int q = tid - 504;
        float z = w_gate[q] * idf[query[b * 8 + q]];
        float m = z;
        m = fmaxf(m, shflx(m, 1)); m = fmaxf(m, shflx(m, 2)); m = fmaxf(m, shflx(m, 4));
        float e = expf(z - m);
        float s = e;
        s += shflx(s, 1); s += shflx(s, 2); s += shflx(s, 4);
        gate_s[q] = e / s;
    }

    if (tid < 240) {
        int q = tid / 30, k = tid - q * 30;
        float s = hist_g[bd * 240 + tid];
        xrow[q][k] = g_in[k] * (s * BN_INV) + b_in[k];
    }
    __syncthreads();

    // layer 1: 30 -> 128 (lane j computes outputs j and j+64); wave wid = q
    {
        float a0 = 0.f, a1 = 0.f;
#pragma unroll
        for (int k = 0; k < 30; ++k) {
            float xk = xrow[wid][k];
            a0 += xk * W0[k * 128 + lane];
            a1 += xk * W0[k * 128 + 64 + lane];
        }
        a0 += b0[lane]; a1 += b0[lane + 64];
        h1s[wid][lane]      = tanhf(g0[lane]      * (a0 * BN_INV) + be0[lane]);
        h1s[wid][lane + 64] = tanhf(g0[lane + 64] * (a1 * BN_INV) + be0[lane + 64]);
    }
    __syncthreads();

    // layer 2: 128 -> 64
    {
        float a = 0.f;
#pragma unroll 8
        for (int k = 0; k < 128; ++k) a += h1s[wid][k] * W1[k * 64 + lane];
        a += b1[lane];
        h2s[wid][lane] = tanhf(g1[lane] * (a * BN_INV) + be1[lane]);
    }
    __syncthreads();

    // layer 3: 64 -> 32
    if (lane < 32) {
        float a = 0.f;
#pragma unroll 8
        for (int k = 0; k < 64; ++k) a += h2s[wid][k] * W2[k * 32 + lane];
        a += b2[lane];
        h3s[wid][lane] = tanhf(g2[lane] * (a * BN_INV) + be2[lane]);
    }
    __syncthreads();

    // layer 4: 32 -> 1, gate weighting
    if (lane == 0) {
        float a = 0.f;
#pragma unroll
        for (int k = 0; k < 32; ++k) a += h3s[wid][k] * W3[k];
        a += b3[0];
        float y = tanhf(g3[0] * (a * BN_INV) + be3[0]);
        part[wid] = gate_s[wid] * y;
    }
    __syncthreads();

    if (tid == 0) {
        float s = 0.f;
#pragma unroll
        for (int q = 0; q < 8; ++q) s += part[q];
        out[bd] = s;
    }
}

extern "C" void kernel_launch(void* const* d_in, const int* in_sizes, int n_in,
                              void* d_out, int out_size, void* d_ws, size_t ws_size,
                              hipStream_t stream) {
    (void)in_sizes; (void)n_in; (void)out_size; (void)ws_size;
    const int*   doc    = (const int*)d_in[0];
    const int*   query  = (const int*)d_in[1];
    const float* emb    = (const float*)d_in[2];
    const float* idf    = (const float*)d_in[3];
    const float* w_gate = (const float*)d_in[4];
    const float* g_in   = (const float*)d_in[5];
    const float* b_in   = (const float*)d_in[6];
    const float* W0  = (const float*)d_in[7];
    const float* b0  = (const float*)d_in[8];
    const float* g0  = (const float*)d_in[9];
    const float* be0 = (const float*)d_in[10];
    const float* W1  = (const float*)d_in[11];
    const float* b1  = (const float*)d_in[12];
    const float* g1  = (const float*)d_in[13];
    const float* be1 = (const float*)d_in[14];
    const float* W2  = (const float*)d_in[15];
    const float* b2  = (const float*)d_in[16];
    const float* g2  = (const float*)d_in[17];
    const float* be2 = (const float*)d_in[18];
    const float* W3  = (const float*)d_in[19];
    const float* b3  = (const float*)d_in[20];
    const float* g3  = (const float*)d_in[21];
    const float* be3 = (const float*)d_in[22];

    float* hist_g = (float*)d_ws;   // 512*240 floats = 491,520 B

    hipMemsetAsync(hist_g, 0, 512 * 240 * sizeof(float), stream);

    drmm_hist<<<dim3(2048), dim3(256), 0, stream>>>(doc, query, emb, hist_g);

    drmm_mlp<<<dim3(512), dim3(512), 0, stream>>>(
        hist_g, query, idf, w_gate, g_in, b_in,
        W0, b0, g0, be0, W1, b1, g1, be1,
        W2, b2, g2, be2, W3, b3, g3, be3,
        (float*)d_out);
}

// Round 4
// 79.633 us; speedup vs baseline: 1.0678x; 1.0678x over previous
//
#include <hip/hip_runtime.h>
#include <math.h>

// DRMM pipeline for MI355X (gfx950) — round 4.
// Phase 1: gather + cosine-sim + histogram. 2048 blocks x 256 thr.
//   block = (bd, token-quarter): 128 tokens, ALL 8 queries.
//   q split across wave-halves (waves 0-1: q0-3, waves 2-3: q4-7); both halves
//   read the same token rows in lockstep -> duplicate read is an L1 hit, HBM
//   traffic stays minimal (~62 MB). qs[4][8]=32 VGPR -> <=64 total -> 8 w/SIMD.
//   All sim arithmetic bit-identical to rounds 1-2 (absmax was 0.0).
// Phase 2: MLP 30->128->64->32->1 + gate softmax + output. 512 blocks x 512 thr.
// B=32, D=16, L=512, Q=8, E=128, NB=30

#define BN_INV 0.99950037468777346f  // np.float32(1/sqrt(1+1e-3))

__device__ __forceinline__ float shflx(float v, int m) {
    return __shfl_xor(v, m, 64);
}

__device__ __forceinline__ float sel4(const float* v, int i) {
    float a = (i & 1) ? v[1] : v[0];
    float b = (i & 1) ? v[3] : v[2];
    return (i & 2) ? b : a;
}

// ---------------- Phase 1: gather + histogram ----------------
// PARTIAL=true: store per-quarter partial hists (no atomics, no memset).
// PARTIAL=false: atomicAdd into a pre-zeroed [512][240] buffer.
template <bool PARTIAL>
__global__ __launch_bounds__(256, 8)
void drmm_hist(const int* __restrict__ doc,
               const int* __restrict__ query,
               const float* __restrict__ emb,
               float* __restrict__ hist_out)
{
    __shared__ float histw[4][4][33];  // [wave][q_local][bin(+pad)]
    __shared__ float qn_s[8];

    const int tid = threadIdx.x;
    const int bid = blockIdx.x;
    const int bd  = bid >> 2;          // 0..511
    const int tq  = bid & 3;           // token quarter
    const int b   = bd >> 4;
    const int wid = tid >> 6;          // wave 0..3
    const int lane = tid & 63;
    const int t16 = tid & 15;
    const int qhalf = wid >> 1;        // 0: q0-3, 1: q4-7
    const int gh  = (wid & 1) * 4 + ((lane >> 4) & 3);  // group-in-half 0..7

    for (int i = tid; i < 4 * 4 * 33; i += 256) ((float*)histw)[i] = 0.0f;

    // 4 query vectors for this wave-half; lane holds its 8-float e-slice.
    float qs[4][8];
#pragma unroll
    for (int q = 0; q < 4; ++q) {
        int qi = query[b * 8 + qhalf * 4 + q];
        const float4* qr = (const float4*)((const char*)emb +
                            (unsigned)qi * 512u + (unsigned)(t16 * 32));
        float4 x0 = qr[0], x1 = qr[1];
        qs[q][0] = x0.x; qs[q][1] = x0.y; qs[q][2] = x0.z; qs[q][3] = x0.w;
        qs[q][4] = x1.x; qs[q][5] = x1.y; qs[q][6] = x1.z; qs[q][7] = x1.w;
    }

    // Query norms (waves 0 and 2; group g computes q_local = g).
    // Same op order as rounds 1-3: per-lane sumsq, sel4, ascending butterfly.
    if ((wid & 1) == 0) {
        int grp = (lane >> 4) & 3;
        float p[4];
#pragma unroll
        for (int q = 0; q < 4; ++q) {
            float s = 0.f;
#pragma unroll
            for (int j = 0; j < 8; ++j) s += qs[q][j] * qs[q][j];
            p[q] = s;
        }
        float s = sel4(p, grp);
        s += shflx(s, 1); s += shflx(s, 2); s += shflx(s, 4); s += shflx(s, 8);
        if (t16 == 0) qn_s[qhalf * 4 + grp] = sqrtf(s);
    }
    __syncthreads();

    const float qn_r = (t16 < 4) ? qn_s[qhalf * 4 + t16] : 0.f;
    const int* docrow = doc + (size_t)bd * 512 + tq * 128;

    // 128 tokens / 8 groups-per-half = 16 iterations. Both q-halves touch the
    // same token rows at the same it -> duplicate global read hits L1.
#pragma unroll 2
    for (int it = 0; it < 16; ++it) {
        int idx = docrow[it * 8 + gh];
        const float4* r = (const float4*)((const char*)emb +
                            (unsigned)idx * 512u + (unsigned)(t16 * 32));
        float4 x0 = r[0], x1 = r[1];
        float v[8] = {x0.x, x0.y, x0.z, x0.w, x1.x, x1.y, x1.z, x1.w};

        float dd = 0.f;
#pragma unroll
        for (int j = 0; j < 8; ++j) dd += v[j] * v[j];
        float dq[4];
#pragma unroll
        for (int q = 0; q < 4; ++q) {
            float s = 0.f;
#pragma unroll
            for (int j = 0; j < 8; ++j) s += v[j] * qs[q][j];
            dq[q] = s;
        }
        // descending butterfly over 16 lanes — identical to rounds 1-2
#pragma unroll
        for (int off = 8; off >= 1; off >>= 1) {
            dd += shflx(dd, off);
#pragma unroll
            for (int q = 0; q < 4; ++q) dq[q] += shflx(dq[q], off);
        }
        if (t16 < 4) {
            float dqq = sel4(dq, t16);
            float sim = dqq / (sqrtf(dd) * qn_r + 1e-8f);
            float u = (sim - 0.001f) / 0.999f * 30.0f;   // ref op order
            int bin = (int)floorf(u);
            bin = bin < 0 ? 0 : (bin > 29 ? 29 : bin);
            atomicAdd(&histw[wid][t16][bin], 1.0f);
        }
    }
    __syncthreads();

    // flush 8q x 30 bins (exact integer counts).
    if (tid < 240) {
        int q = tid / 30, k = tid - q * 30;
        float s = (q < 4)
                ? histw[0][q][k] + histw[1][q][k]
                : histw[2][q - 4][k] + histw[3][q - 4][k];
        if (PARTIAL) {
            hist_out[((size_t)bd * 4 + tq) * 240 + tid] = s;
        } else {
            atomicAdd(&hist_out[bd * 240 + tid], s);
        }
    }
}

// ---------------- Phase 2: gate softmax + MLP + output ----------------
template <bool PARTIAL>
__global__ __launch_bounds__(512, 4)
void drmm_mlp(const float* __restrict__ hist_g,
              const int* __restrict__ query,
              const float* __restrict__ idf,
              const float* __restrict__ w_gate,
              const float* __restrict__ g_in, const float* __restrict__ b_in,
              const float* __restrict__ W0, const float* __restrict__ b0,
              const float* __restrict__ g0, const float* __restrict__ be0,
              const float* __restrict__ W1, const float* __restrict__ b1,
              const float* __restrict__ g1, const float* __restrict__ be1,
              const float* __restrict__ W2, const float* __restrict__ b2,
              const float* __restrict__ g2, const float* __restrict__ be2,
              const float* __restrict__ W3, const float* __restrict__ b3,
              const float* __restrict__ g3, const float* __restrict__ be3,
              float* __restrict__ out)
{
    __shared__ float xrow[8][30];
    __shared__ float h1s[8][128];
    __shared__ float h2s[8][64];
    __shared__ float h3s[8][32];
    __shared__ float gate_s[8];
    __shared__ float part[8];

    const int tid  = threadIdx.x;
    const int bd   = blockIdx.x;
    const int b    = bd >> 4;
    const int wid  = tid >> 6;
    const int lane = tid & 63;

    // Gate softmax: 8 parallel lanes (same op order as rounds 2-3).
    if (tid >= 504) {
        int q = tid - 504;
        float z = w_gate[q] * idf[query[b * 8 + q]];
        float m = z;
        m = fmaxf(m, shflx(m, 1)); m = fmaxf(m, shflx(m, 2)); m = fmaxf(m, shflx(m, 4));
        float e = expf(z - m);
        float s = e;
        s += shflx(s, 1); s += shflx(s, 2); s += shflx(s, 4);
        gate_s[q] = e / s;
    }

    if (tid < 240) {
        int q = tid / 30, k = tid - q * 30;
        float s;
        if (PARTIAL) {
            const float* hp = hist_g + (size_t)bd * 4 * 240 + tid;
            s = hp[0] + hp[240] + hp[480] + hp[720];  // exact int counts
        } else {
            s = hist_g[bd * 240 + tid];
        }
        xrow[q][k] = g_in[k] * (s * BN_INV) + b_in[k];
    }
    __syncthreads();

    // layer 1: 30 -> 128 (lane j computes outputs j and j+64); wave wid = q
    {
        float a0 = 0.f, a1 = 0.f;
#pragma unroll
        for (int k = 0; k < 30; ++k) {
            float xk = xrow[wid][k];
            a0 += xk * W0[k * 128 + lane];
            a1 += xk * W0[k * 128 + 64 + lane];
        }
        a0 += b0[lane]; a1 += b0[lane + 64];
        h1s[wid][lane]      = tanhf(g0[lane]      * (a0 * BN_INV) + be0[lane]);
        h1s[wid][lane + 64] = tanhf(g0[lane + 64] * (a1 * BN_INV) + be0[lane + 64]);
    }
    __syncthreads();

    // layer 2: 128 -> 64
    {
        float a = 0.f;
#pragma unroll 8
        for (int k = 0; k < 128; ++k) a += h1s[wid][k] * W1[k * 64 + lane];
        a += b1[lane];
        h2s[wid][lane] = tanhf(g1[lane] * (a * BN_INV) + be1[lane]);
    }
    __syncthreads();

    // layer 3: 64 -> 32
    if (lane < 32) {
        float a = 0.f;
#pragma unroll 8
        for (int k = 0; k < 64; ++k) a += h2s[wid][k] * W2[k * 32 + lane];
        a += b2[lane];
        h3s[wid][lane] = tanhf(g2[lane] * (a * BN_INV) + be2[lane]);
    }
    __syncthreads();

    // layer 4: 32 -> 1, gate weighting
    if (lane == 0) {
        float a = 0.f;
#pragma unroll
        for (int k = 0; k < 32; ++k) a += h3s[wid][k] * W3[k];
        a += b3[0];
        float y = tanhf(g3[0] * (a * BN_INV) + be3[0]);
        part[wid] = gate_s[wid] * y;
    }
    __syncthreads();

    if (tid == 0) {
        float s = 0.f;
#pragma unroll
        for (int q = 0; q < 8; ++q) s += part[q];
        out[bd] = s;
    }
}

extern "C" void kernel_launch(void* const* d_in, const int* in_sizes, int n_in,
                              void* d_out, int out_size, void* d_ws, size_t ws_size,
                              hipStream_t stream) {
    (void)in_sizes; (void)n_in; (void)out_size;
    const int*   doc    = (const int*)d_in[0];
    const int*   query  = (const int*)d_in[1];
    const float* emb    = (const float*)d_in[2];
    const float* idf    = (const float*)d_in[3];
    const float* w_gate = (const float*)d_in[4];
    const float* g_in   = (const float*)d_in[5];
    const float* b_in   = (const float*)d_in[6];
    const float* W0  = (const float*)d_in[7];
    const float* b0  = (const float*)d_in[8];
    const float* g0  = (const float*)d_in[9];
    const float* be0 = (const float*)d_in[10];
    const float* W1  = (const float*)d_in[11];
    const float* b1  = (const float*)d_in[12];
    const float* g1  = (const float*)d_in[13];
    const float* be1 = (const float*)d_in[14];
    const float* W2  = (const float*)d_in[15];
    const float* b2  = (const float*)d_in[16];
    const float* g2  = (const float*)d_in[17];
    const float* be2 = (const float*)d_in[18];
    const float* W3  = (const float*)d_in[19];
    const float* b3  = (const float*)d_in[20];
    const float* g3  = (const float*)d_in[21];
    const float* be3 = (const float*)d_in[22];

    float* hist_g = (float*)d_ws;
    const size_t need_partial = (size_t)512 * 4 * 240 * sizeof(float); // 1.97 MB

    if (ws_size >= need_partial) {
        drmm_hist<true><<<dim3(2048), dim3(256), 0, stream>>>(doc, query, emb, hist_g);
        drmm_mlp<true><<<dim3(512), dim3(512), 0, stream>>>(
            hist_g, query, idf, w_gate, g_in, b_in,
            W0, b0, g0, be0, W1, b1, g1, be1,
            W2, b2, g2, be2, W3, b3, g3, be3, (float*)d_out);
    } else {
        hipMemsetAsync(hist_g, 0, 512 * 240 * sizeof(float), stream);
        drmm_hist<false><<<dim3(2048), dim3(256), 0, stream>>>(doc, query, emb, hist_g);
        drmm_mlp<false><<<dim3(512), dim3(512), 0, stream>>>(
            hist_g, query, idf, w_gate, g_in, b_in,
            W0, b0, g0, be0, W1, b1, g1, be1,
            W2, b2, g2, be2, W3, b3, g3, be3, (float*)d_out);
    }
}

// Round 5
// 63.786 us; speedup vs baseline: 1.3331x; 1.2484x over previous
//
#include <hip/hip_runtime.h>
#include <math.h>

// DRMM pipeline for MI355X (gfx950) — round 5: lane-owns-token transpose.
// Phase 1: 1024 blocks x 256 thr; lane = one doc token. Streams its 512B row
//   (32 x float4), accumulates dd + dq[8] fully in-register (NO shuffles).
//   Query vectors read via wave-uniform addresses (scalarizable). Histogram
//   via per-wave LDS float atomics; per-(bd,half) partials to d_ws.
// Phase 2: MLP 30->128->64->32->1 + gate softmax + output. 512 blocks x 512 thr.
// B=32, D=16, L=512, Q=8, E=128, NB=30

#define BN_INV 0.99950037468777346f  // np.float32(1/sqrt(1+1e-3))

__device__ __forceinline__ float shflx(float v, int m) {
    return __shfl_xor(v, m, 64);
}

__device__ __forceinline__ int sel8i(int v0, int v1, int v2, int v3,
                                     int v4, int v5, int v6, int v7, int i) {
    int a0 = (i & 1) ? v1 : v0;
    int a1 = (i & 1) ? v3 : v2;
    int a2 = (i & 1) ? v5 : v4;
    int a3 = (i & 1) ? v7 : v6;
    int b0 = (i & 2) ? a1 : a0;
    int b1 = (i & 2) ? a3 : a2;
    return (i & 4) ? b1 : b0;
}

// ---------------- Phase 1: gather + histogram (lane-per-token) ----------------
template <bool PARTIAL>
__global__ __launch_bounds__(256, 4)
void drmm_hist(const int* __restrict__ doc,
               const int* __restrict__ query,
               const float* __restrict__ emb,
               float* __restrict__ hist_out)
{
    __shared__ float histw[4][8][32];   // [wave][q][bin(+2 pad)]
    __shared__ float qn_s[8];

    const int tid  = threadIdx.x;
    const int bid  = blockIdx.x;        // (bd, token-half)
    const int bd   = bid >> 1;
    const int b    = bid >> 5;          // bd >> 4
    const int wid  = tid >> 6;
    const int lane = tid & 63;

    for (int i = tid; i < 4 * 8 * 32; i += 256) ((float*)histw)[i] = 0.0f;

    // wave-uniform query row indices
    const int* qrow = query + b * 8;
    const int qi0 = __builtin_amdgcn_readfirstlane(qrow[0]);
    const int qi1 = __builtin_amdgcn_readfirstlane(qrow[1]);
    const int qi2 = __builtin_amdgcn_readfirstlane(qrow[2]);
    const int qi3 = __builtin_amdgcn_readfirstlane(qrow[3]);
    const int qi4 = __builtin_amdgcn_readfirstlane(qrow[4]);
    const int qi5 = __builtin_amdgcn_readfirstlane(qrow[5]);
    const int qi6 = __builtin_amdgcn_readfirstlane(qrow[6]);
    const int qi7 = __builtin_amdgcn_readfirstlane(qrow[7]);

    const float4* qf0 = (const float4*)(emb + (size_t)qi0 * 128);
    const float4* qf1 = (const float4*)(emb + (size_t)qi1 * 128);
    const float4* qf2 = (const float4*)(emb + (size_t)qi2 * 128);
    const float4* qf3 = (const float4*)(emb + (size_t)qi3 * 128);
    const float4* qf4 = (const float4*)(emb + (size_t)qi4 * 128);
    const float4* qf5 = (const float4*)(emb + (size_t)qi5 * 128);
    const float4* qf6 = (const float4*)(emb + (size_t)qi6 * 128);
    const float4* qf7 = (const float4*)(emb + (size_t)qi7 * 128);

    // query norms: wave 0, lane = q*8 + j; j covers 16 floats.
    if (wid == 0) {
        int q = lane >> 3, j = lane & 7;
        int qis = sel8i(qi0, qi1, qi2, qi3, qi4, qi5, qi6, qi7, q);
        const float4* qq = (const float4*)(emb + (size_t)qis * 128) + j * 4;
        float s = 0.f;
#pragma unroll
        for (int c = 0; c < 4; ++c) {
            float4 x = qq[c];
            s = fmaf(x.x, x.x, s); s = fmaf(x.y, x.y, s);
            s = fmaf(x.z, x.z, s); s = fmaf(x.w, x.w, s);
        }
        s += shflx(s, 1); s += shflx(s, 2); s += shflx(s, 4);
        if (j == 0) qn_s[q] = sqrtf(s);
    }
    __syncthreads();

    // ---- per-lane token streaming ----
    const int gtok = bid * 256 + tid;          // 0..262143
    const int idx  = doc[gtok];
    const float4* rp = (const float4*)(emb + (size_t)idx * 128);

    float dd = 0.f;
    float dq0 = 0.f, dq1 = 0.f, dq2 = 0.f, dq3 = 0.f;
    float dq4 = 0.f, dq5 = 0.f, dq6 = 0.f, dq7 = 0.f;

#pragma unroll 4
    for (int s = 0; s < 32; ++s) {
        float4 v  = rp[s];
        float4 a0 = qf0[s], a1 = qf1[s], a2 = qf2[s], a3 = qf3[s];
        float4 a4 = qf4[s], a5 = qf5[s], a6 = qf6[s], a7 = qf7[s];
        dd  = fmaf(v.x, v.x, dd);  dd  = fmaf(v.y, v.y, dd);
        dd  = fmaf(v.z, v.z, dd);  dd  = fmaf(v.w, v.w, dd);
#define ACC(A, Dq) Dq = fmaf(v.x, A.x, Dq); Dq = fmaf(v.y, A.y, Dq); \
                   Dq = fmaf(v.z, A.z, Dq); Dq = fmaf(v.w, A.w, Dq);
        ACC(a0, dq0) ACC(a1, dq1) ACC(a2, dq2) ACC(a3, dq3)
        ACC(a4, dq4) ACC(a5, dq5) ACC(a6, dq6) ACC(a7, dq7)
#undef ACC
    }

    const float dn = sqrtf(dd);
#define DOBIN(J, DQ) {                                                  \
        float sim = DQ / (dn * qn_s[J] + 1e-8f);                        \
        float u = (sim - 0.001f) / 0.999f * 30.0f;                      \
        int bin = (int)floorf(u);                                       \
        bin = bin < 0 ? 0 : (bin > 29 ? 29 : bin);                      \
        atomicAdd(&histw[wid][J][bin], 1.0f);                           \
    }
    DOBIN(0, dq0) DOBIN(1, dq1) DOBIN(2, dq2) DOBIN(3, dq3)
    DOBIN(4, dq4) DOBIN(5, dq5) DOBIN(6, dq6) DOBIN(7, dq7)
#undef DOBIN
    __syncthreads();

    // flush 8q x 30 bins (exact integer counts)
    if (tid < 240) {
        int q = tid / 30, k = tid - q * 30;
        float s = histw[0][q][k] + histw[1][q][k]
                + histw[2][q][k] + histw[3][q][k];
        if (PARTIAL) {
            hist_out[(size_t)bid * 240 + tid] = s;
        } else {
            atomicAdd(&hist_out[bd * 240 + tid], s);
        }
    }
}

// ---------------- Phase 2: gate softmax + MLP + output ----------------
template <bool PARTIAL>
__global__ __launch_bounds__(512, 4)
void drmm_mlp(const float* __restrict__ hist_g,
              const int* __restrict__ query,
              const float* __restrict__ idf,
              const float* __restrict__ w_gate,
              const float* __restrict__ g_in, const float* __restrict__ b_in,
              const float* __restrict__ W0, const float* __restrict__ b0,
              const float* __restrict__ g0, const float* __restrict__ be0,
              const float* __restrict__ W1, const float* __restrict__ b1,
              const float* __restrict__ g1, const float* __restrict__ be1,
              const float* __restrict__ W2, const float* __restrict__ b2,
              const float* __restrict__ g2, const float* __restrict__ be2,
              const float* __restrict__ W3, const float* __restrict__ b3,
              const float* __restrict__ g3, const float* __restrict__ be3,
              float* __restrict__ out)
{
    __shared__ float xrow[8][30];
    __shared__ float h1s[8][128];
    __shared__ float h2s[8][64];
    __shared__ float h3s[8][32];
    __shared__ float gate_s[8];
    __shared__ float part[8];

    const int tid  = threadIdx.x;
    const int bd   = blockIdx.x;
    const int b    = bd >> 4;
    const int wid  = tid >> 6;
    const int lane = tid & 63;

    // Gate softmax: 8 parallel lanes (same op order as rounds 2-4).
    if (tid >= 504) {
        int q = tid - 504;
        float z = w_gate[q] * idf[query[b * 8 + q]];
        float m = z;
        m = fmaxf(m, shflx(m, 1)); m = fmaxf(m, shflx(m, 2)); m = fmaxf(m, shflx(m, 4));
        float e = expf(z - m);
        float s = e;
        s += shflx(s, 1); s += shflx(s, 2); s += shflx(s, 4);
        gate_s[q] = e / s;
    }

    if (tid < 240) {
        int q = tid / 30, k = tid - q * 30;
        float s;
        if (PARTIAL) {
            const float* hp = hist_g + (size_t)bd * 480 + tid;
            s = hp[0] + hp[240];  // exact int counts
        } else {
            s = hist_g[bd * 240 + tid];
        }
        xrow[q][k] = g_in[k] * (s * BN_INV) + b_in[k];
    }
    __syncthreads();

    // layer 1: 30 -> 128 (lane j computes outputs j and j+64); wave wid = q
    {
        float a0 = 0.f, a1 = 0.f;
#pragma unroll
        for (int k = 0; k < 30; ++k) {
            float xk = xrow[wid][k];
            a0 += xk * W0[k * 128 + lane];
            a1 += xk * W0[k * 128 + 64 + lane];
        }
        a0 += b0[lane]; a1 += b0[lane + 64];
        h1s[wid][lane]      = tanhf(g0[lane]      * (a0 * BN_INV) + be0[lane]);
        h1s[wid][lane + 64] = tanhf(g0[lane + 64] * (a1 * BN_INV) + be0[lane + 64]);
    }
    __syncthreads();

    // layer 2: 128 -> 64
    {
        float a = 0.f;
#pragma unroll 8
        for (int k = 0; k < 128; ++k) a += h1s[wid][k] * W1[k * 64 + lane];
        a += b1[lane];
        h2s[wid][lane] = tanhf(g1[lane] * (a * BN_INV) + be1[lane]);
    }
    __syncthreads();

    // layer 3: 64 -> 32
    if (lane < 32) {
        float a = 0.f;
#pragma unroll 8
        for (int k = 0; k < 64; ++k) a += h2s[wid][k] * W2[k * 32 + lane];
        a += b2[lane];
        h3s[wid][lane] = tanhf(g2[lane] * (a * BN_INV) + be2[lane]);
    }
    __syncthreads();

    // layer 4: 32 -> 1, gate weighting
    if (lane == 0) {
        float a = 0.f;
#pragma unroll
        for (int k = 0; k < 32; ++k) a += h3s[wid][k] * W3[k];
        a += b3[0];
        float y = tanhf(g3[0] * (a * BN_INV) + be3[0]);
        part[wid] = gate_s[wid] * y;
    }
    __syncthreads();

    if (tid == 0) {
        float s = 0.f;
#pragma unroll
        for (int q = 0; q < 8; ++q) s += part[q];
        out[bd] = s;
    }
}

extern "C" void kernel_launch(void* const* d_in, const int* in_sizes, int n_in,
                              void* d_out, int out_size, void* d_ws, size_t ws_size,
                              hipStream_t stream) {
    (void)in_sizes; (void)n_in; (void)out_size;
    const int*   doc    = (const int*)d_in[0];
    const int*   query  = (const int*)d_in[1];
    const float* emb    = (const float*)d_in[2];
    const float* idf    = (const float*)d_in[3];
    const float* w_gate = (const float*)d_in[4];
    const float* g_in   = (const float*)d_in[5];
    const float* b_in   = (const float*)d_in[6];
    const float* W0  = (const float*)d_in[7];
    const float* b0  = (const float*)d_in[8];
    const float* g0  = (const float*)d_in[9];
    const float* be0 = (const float*)d_in[10];
    const float* W1  = (const float*)d_in[11];
    const float* b1  = (const float*)d_in[12];
    const float* g1  = (const float*)d_in[13];
    const float* be1 = (const float*)d_in[14];
    const float* W2  = (const float*)d_in[15];
    const float* b2  = (const float*)d_in[16];
    const float* g2  = (const float*)d_in[17];
    const float* be2 = (const float*)d_in[18];
    const float* W3  = (const float*)d_in[19];
    const float* b3  = (const float*)d_in[20];
    const float* g3  = (const float*)d_in[21];
    const float* be3 = (const float*)d_in[22];

    float* hist_g = (float*)d_ws;
    const size_t need_partial = (size_t)1024 * 240 * sizeof(float); // 983 KB

    if (ws_size >= need_partial) {
        drmm_hist<true><<<dim3(1024), dim3(256), 0, stream>>>(doc, query, emb, hist_g);
        drmm_mlp<true><<<dim3(512), dim3(512), 0, stream>>>(
            hist_g, query, idf, w_gate, g_in, b_in,
            W0, b0, g0, be0, W1, b1, g1, be1,
            W2, b2, g2, be2, W3, b3, g3, be3, (float*)d_out);
    } else {
        hipMemsetAsync(hist_g, 0, 512 * 240 * sizeof(float), stream);
        drmm_hist<false><<<dim3(1024), dim3(256), 0, stream>>>(doc, query, emb, hist_g);
        drmm_mlp<false><<<dim3(512), dim3(512), 0, stream>>>(
            hist_g, query, idf, w_gate, g_in, b_in,
            W0, b0, g0, be0, W1, b1, g1, be1,
            W2, b2, g2, be2, W3, b3, g3, be3, (float*)d_out);
    }
}